// Round 16
// baseline (181.352 us; speedup 1.0000x reference)
//
#include <hip/hip_runtime.h>

#define N_PTS 16384
#define KNN   16
#define CIN   64
#define SDIM  8

typedef __bf16 bf16x8 __attribute__((ext_vector_type(8)));
typedef float  f32x4  __attribute__((ext_vector_type(4)));

// ---------------- K1: s = x @ Ws^T + bs (f64 master for re-rank) + packed MFMA operand
// vectors for the distance GEMM.
// qvec[i] (K=32 bf16): [hi(8), hi(8), lo(8), sqi_hi, sqi_lo, 1, 1, 1, 0,0,0]
// cvec[j] (K=32 bf16): [-2hi(8), -2lo(8), -2hi(8), 1, 1, sqj_hi, sqj_lo, eps, 0,0,0]
// => dot = eps + sqi + sqj - 2*(a_hi b_hi + a_hi b_lo + a_lo b_hi) ~= d2 + eps > 0.
__global__ __launch_bounds__(64) void k_proj(
    const float* __restrict__ x, const float* __restrict__ Ws, const float* __restrict__ bs,
    __bf16* __restrict__ qvec, __bf16* __restrict__ cvec, double* __restrict__ s64) {
  __shared__ double w[SDIM * CIN];
  __shared__ double bsh[SDIM];
  int tid = threadIdx.x;
  for (int t = tid; t < SDIM * CIN; t += 64) w[t] = (double)Ws[t];
  if (tid < SDIM) bsh[tid] = (double)bs[tid];
  __syncthreads();
  int i = blockIdx.x * 64 + tid;
  double acc[SDIM];
#pragma unroll
  for (int d = 0; d < SDIM; ++d) acc[d] = bsh[d];
  for (int j = 0; j < CIN; j += 4) {
    float4 xv = *(const float4*)(x + (size_t)i * CIN + j);
#pragma unroll
    for (int d = 0; d < SDIM; ++d) {
      acc[d] = fma((double)xv.x, w[d * CIN + j + 0], acc[d]);
      acc[d] = fma((double)xv.y, w[d * CIN + j + 1], acc[d]);
      acc[d] = fma((double)xv.z, w[d * CIN + j + 2], acc[d]);
      acc[d] = fma((double)xv.w, w[d * CIN + j + 3], acc[d]);
    }
  }
  float sf[8];
  float sq = 0.f;
#pragma unroll
  for (int d = 0; d < SDIM; ++d) {
    sf[d] = (float)acc[d];
    s64[(size_t)i * SDIM + d] = acc[d];
    sq = fmaf(sf[d], sf[d], sq);
  }
  __bf16 av[32], bv[32];
#pragma unroll
  for (int d = 0; d < 8; ++d) {
    __bf16 hi = (__bf16)sf[d];
    float hif = (float)hi;
    __bf16 lo = (__bf16)(sf[d] - hif);
    av[d] = hi; av[8 + d] = hi; av[16 + d] = lo;
    __bf16 h2 = (__bf16)(-2.f * hif);          // exact (x2 is exponent bump)
    __bf16 l2 = (__bf16)(-2.f * (float)lo);    // exact
    bv[d] = h2; bv[8 + d] = l2; bv[16 + d] = h2;
  }
  __bf16 sqh = (__bf16)sq;
  __bf16 sql = (__bf16)(sq - (float)sqh);
  __bf16 one = (__bf16)1.0f, zero = (__bf16)0.0f;
  __bf16 eps = (__bf16)0.0009765625f;  // 2^-10, exact in bf16
  av[24] = sqh; av[25] = sql; av[26] = one; av[27] = one;
  av[28] = one; av[29] = av[30] = av[31] = zero;
  bv[24] = one; bv[25] = one; bv[26] = sqh; bv[27] = sql;
  bv[28] = eps; bv[29] = bv[30] = bv[31] = zero;
  uint4* ap = (uint4*)av;
  uint4* bpv = (uint4*)bv;
  uint4* da = (uint4*)(qvec + (size_t)i * 32);
  uint4* db = (uint4*)(cvec + (size_t)i * 32);
  da[0] = ap[0]; da[1] = ap[1]; da[2] = ap[2]; da[3] = ap[3];
  db[0] = bpv[0]; db[1] = bpv[1]; db[2] = bpv[2]; db[3] = bpv[3];
}

__device__ inline unsigned bitonic64(unsigned key, int lane) {
#pragma unroll
  for (int size = 2; size <= 64; size <<= 1) {
#pragma unroll
    for (int stride = size >> 1; stride > 0; stride >>= 1) {
      unsigned other = __shfl_xor(key, stride, 64);
      bool takeMin = (((lane & size) == 0) == ((lane & stride) == 0));
      unsigned mn = min(key, other), mx = max(key, other);
      key = takeMin ? mn : mx;
    }
  }
  return key;
}

// ---------------- K2: MFMA distance tiles, A=candidates(rows), B=queries(cols).
// 4 waves/block, double-buffered MFMA results, ring depth 32, branchless accept.
// Storm v2: BATCHED ring reads (32 pipelined ds_reads into registers, one latency
// instead of ~25 serialized dependent reads) + de-branched insert chains in groups
// of 8 (4 early-out branches instead of ~64 per-iteration guards). Semantics
// identical: same inserts in same order; i>=cnt lanes insert 0xFFFFFFFF (identity).
__global__ __launch_bounds__(256, 4) void k_dist(
    const __bf16* __restrict__ qvec, const __bf16* __restrict__ cvec,
    unsigned* __restrict__ partial) {
  __shared__ unsigned ring[32 * 256];   // ring[slot*256+tid]: bank=tid%32, conflict-free
  const int tid = threadIdx.x;
  const int lane = tid & 63;
  const int wv = tid >> 6;
  const int e = lane & 15, g = lane >> 4;
  const int qidx = blockIdx.x * 64 + wv * 16 + e;   // this lane's query
  const int cbase = blockIdx.y * 4096;

  bf16x8 Qf = *(const bf16x8*)(qvec + (size_t)qidx * 32 + g * 8);  // B-frag (fixed)

  unsigned kk[16];
#pragma unroll
  for (int r = 0; r < 16; ++r) kk[r] = 0xFFFFFFFFu;
  float thr = __uint_as_float(0x7F800000u);  // +inf (shared across query quad)
  unsigned cnt = 0;

  const __bf16* cp = cvec + (size_t)(cbase + e) * 32 + g * 8;
  f32x4 zero4 = (f32x4){0.f, 0.f, 0.f, 0.f};
  const unsigned cb0 = (unsigned)(cbase + 4 * g);

  auto consume4 = [&](const f32x4& v, unsigned cb) {
#pragma unroll
    for (int j = 0; j < 4; ++j) {
      unsigned key = (__float_as_uint(v[j]) & 0xFFFFC000u) | (cb + j);  // v_and_or_b32
      ring[(cnt << 8) | (unsigned)tid] = key;     // unconditional write
      cnt += (v[j] < thr) ? 1u : 0u;              // branchless accept
    }
  };
  auto storm = [&]() {
    unsigned rk[32];
#pragma unroll
    for (int i = 0; i < 32; ++i) rk[i] = ring[(i << 8) | (unsigned)tid];  // batched reads
#define INS1(i) { unsigned key_ = ((i) < (int)cnt) ? rk[(i)] : 0xFFFFFFFFu;      \
    _Pragma("unroll")                                                            \
    for (int r = 15; r > 0; --r) kk[r] = max(kk[r - 1], min(kk[r], key_));       \
    kk[0] = min(kk[0], key_); }
#define INS8(b) INS1((b)+0) INS1((b)+1) INS1((b)+2) INS1((b)+3)                  \
                INS1((b)+4) INS1((b)+5) INS1((b)+6) INS1((b)+7)
    do {
      if (!__any((int)cnt > 0)) break;
      INS8(0)
      if (!__any((int)cnt > 8)) break;
      INS8(8)
      if (!__any((int)cnt > 16)) break;
      INS8(16)
      if (!__any((int)cnt > 24)) break;
      INS8(24)
    } while (0);
#undef INS1
#undef INS8
    cnt = 0;
    unsigned tbk = min((kk[15] >> 14) + 1u, 0x1FE00u);  // bucket+1, saturating
    thr = __uint_as_float(tbk << 14);
    // share: query-quad min of thresholds (lanes e, e+16, e+32, e+48)
    thr = fminf(thr, __shfl_xor(thr, 16, 64));
    thr = fminf(thr, __shfl_xor(thr, 32, 64));
  };

#define LOADG(B, grp) { const __bf16* np_ = cp + (size_t)(grp) * 2048;           \
    B##0 = *(const bf16x8*)(np_);        B##1 = *(const bf16x8*)(np_ + 512);     \
    B##2 = *(const bf16x8*)(np_ + 1024); B##3 = *(const bf16x8*)(np_ + 1536); }
#define MFMAG(C, B) {                                                            \
    C##0 = __builtin_amdgcn_mfma_f32_16x16x32_bf16(B##0, Qf, zero4, 0, 0, 0);    \
    C##1 = __builtin_amdgcn_mfma_f32_16x16x32_bf16(B##1, Qf, zero4, 0, 0, 0);    \
    C##2 = __builtin_amdgcn_mfma_f32_16x16x32_bf16(B##2, Qf, zero4, 0, 0, 0);    \
    C##3 = __builtin_amdgcn_mfma_f32_16x16x32_bf16(B##3, Qf, zero4, 0, 0, 0); }
#define CONSG(C, grp) { unsigned cb_ = cb0 + (unsigned)(grp) * 64u;              \
    consume4(C##0, cb_); consume4(C##1, cb_ + 16); consume4(C##2, cb_ + 32);     \
    consume4(C##3, cb_ + 48);                                                    \
    if (__any(cnt >= 17)) storm(); }

  bf16x8 a00, a01, a02, a03, a10, a11, a12, a13;
  f32x4 c00, c01, c02, c03, c10, c11, c12, c13;

  // 64 groups of 4 tiles (16 candidates/lane each), 2-group software pipeline
  LOADG(a0, 0)
  LOADG(a1, 1)
  MFMAG(c0, a0)                       // group 0 in flight
  for (int gr = 0; gr < 62; gr += 2) {
    LOADG(a0, gr + 2)                 // a0's MFMAs already issued
    MFMAG(c1, a1)                     // group gr+1 in flight
    CONSG(c0, gr)                     // consume landed group gr
    LOADG(a1, gr + 3)
    MFMAG(c0, a0)                     // group gr+2 in flight
    CONSG(c1, gr + 1)
  }
  MFMAG(c1, a1)                       // group 63
  CONSG(c0, 62)
  CONSG(c1, 63)
  storm();  // final flush -> kk sorted ascending
#undef LOADG
#undef MFMAG
#undef CONSG

  unsigned* p = partial + (size_t)qidx * 256 + (size_t)blockIdx.y * 64 + g * 16;
  *(uint4*)(p + 0)  = make_uint4(kk[0], kk[1], kk[2], kk[3]);
  *(uint4*)(p + 4)  = make_uint4(kk[4], kk[5], kk[6], kk[7]);
  *(uint4*)(p + 8)  = make_uint4(kk[8], kk[9], kk[10], kk[11]);
  *(uint4*)(p + 12) = make_uint4(kk[12], kk[13], kk[14], kk[15]);
}

// ---------------- K3: fused reduce (256 keys -> 64 via 4 bitonic-64) + exact f64 re-rank,
// bitonic sort on (d2,f64|idx), keep 16.
__global__ __launch_bounds__(256) void k_merge(
    const double* __restrict__ s64, const unsigned* __restrict__ partial,
    unsigned short* __restrict__ fin) {
  int lane = threadIdx.x & 63;
  int node = blockIdx.x * 4 + (threadIdx.x >> 6);
  unsigned jc = 0;
#pragma unroll
  for (int t = 0; t < 4; ++t) {
    unsigned key = partial[(size_t)node * 256 + t * 64 + lane];
    key = bitonic64(key, lane);
    unsigned k16 = __shfl(key, lane & 15, 64);  // top-16 live in lanes 0..15
    if ((lane >> 4) == t) jc = k16 & 0x3FFFu;
  }
  const double* si = s64 + (size_t)node * 8;
  const double* sj = s64 + (size_t)jc * 8;
  double d2 = 0.0;
#pragma unroll
  for (int d = 0; d < 8; ++d) { double t = si[d] - sj[d]; d2 = fma(t, t, d2); }
  unsigned long long key =
      (((unsigned long long)__double_as_longlong(d2)) & ~0x3FFFull) | (unsigned long long)jc;
#pragma unroll
  for (int size = 2; size <= 64; size <<= 1) {
#pragma unroll
    for (int stride = size >> 1; stride > 0; stride >>= 1) {
      unsigned lo = __shfl_xor((unsigned)key, stride, 64);
      unsigned hi = __shfl_xor((unsigned)(key >> 32), stride, 64);
      unsigned long long other = ((unsigned long long)hi << 32) | lo;
      bool takeMin = (((lane & size) == 0) == ((lane & stride) == 0));
      unsigned long long mn = key < other ? key : other;
      unsigned long long mx = key < other ? other : key;
      key = takeMin ? mn : mx;
    }
  }
  if (lane < 16) fin[(size_t)node * 16 + lane] = (unsigned short)(key & 0x3FFFull);
}

// ---------------- K4: gather + MLP (bf16 MFMA 16x16x32, f32 accum), LN, relu, mean over K
__device__ inline bf16x8 pack8(float4 a, float4 b) {
  bf16x8 r;
  r[0] = (__bf16)a.x; r[1] = (__bf16)a.y; r[2] = (__bf16)a.z; r[3] = (__bf16)a.w;
  r[4] = (__bf16)b.x; r[5] = (__bf16)b.y; r[6] = (__bf16)b.z; r[7] = (__bf16)b.w;
  return r;
}
__device__ inline float4 sub4(float4 a, float4 b) {
  return make_float4(a.x - b.x, a.y - b.y, a.z - b.z, a.w - b.w);
}
// LN over 64 channels of each edge-row, then affine + relu.
// acc[nt][j]: row (4*g + j), channel nt*16 + e  (C/D layout: col=lane&15, row=(lane>>4)*4+reg)
__device__ inline void ln_relu(const f32x4 acc[4], const float bc[4], const float gc[4],
                               const float bec[4], float nh[4][4]) {
#pragma unroll
  for (int j = 0; j < 4; ++j) {
    float v0 = acc[0][j] + bc[0], v1 = acc[1][j] + bc[1];
    float v2 = acc[2][j] + bc[2], v3 = acc[3][j] + bc[3];
    float t = v0 + v1 + v2 + v3;
    float qq = v0 * v0 + v1 * v1 + v2 * v2 + v3 * v3;
#pragma unroll
    for (int m = 1; m < 16; m <<= 1) {
      t += __shfl_xor(t, m, 64);
      qq += __shfl_xor(qq, m, 64);
    }
    float mean = t * (1.f / 64.f);
    float var = qq * (1.f / 64.f) - mean * mean;
    float rstd = rsqrtf(var + 1e-5f);
    nh[0][j] = fmaxf((v0 - mean) * rstd * gc[0] + bec[0], 0.f);
    nh[1][j] = fmaxf((v1 - mean) * rstd * gc[1] + bec[1], 0.f);
    nh[2][j] = fmaxf((v2 - mean) * rstd * gc[2] + bec[2], 0.f);
    nh[3][j] = fmaxf((v3 - mean) * rstd * gc[3] + bec[3], 0.f);
  }
}

// __launch_bounds__(256, 2): grid gives 2 waves/SIMD; raise VGPR cap so the
// gather software pipeline (2-deep nbr queue + next-node feature registers)
// survives register allocation.
__global__ __launch_bounds__(256, 2) void k_mlp(
    const float* __restrict__ x, const unsigned short* __restrict__ nbr,
    const float* __restrict__ W1, const float* __restrict__ b1,
    const float* __restrict__ g1v, const float* __restrict__ be1,
    const float* __restrict__ W2, const float* __restrict__ b2,
    const float* __restrict__ g2v, const float* __restrict__ be2,
    float* __restrict__ out) {
  __shared__ float tr[4][16 * 68];
  const int lane = threadIdx.x & 63;
  const int wv = threadIdx.x >> 6;
  const int e = lane & 15;  // A row (edge) / B,C col (channel within tile)
  const int g = lane >> 4;  // k-group of 8

  // B fragments: lane holds B[k=(lane>>4)*8+u][col=lane&15]; B[k][c] = W^T[k][c] = W[c][k]
  bf16x8 B1[4][4];
#pragma unroll
  for (int ks = 0; ks < 4; ++ks)
#pragma unroll
    for (int nt = 0; nt < 4; ++nt) {
      const float* wr = W1 + (size_t)(nt * 16 + e) * 128 + ks * 32 + g * 8;
#pragma unroll
      for (int u = 0; u < 8; ++u) B1[ks][nt][u] = (__bf16)wr[u];
    }
  bf16x8 B2[2][4];
#pragma unroll
  for (int ks = 0; ks < 2; ++ks)
#pragma unroll
    for (int nt = 0; nt < 4; ++nt) {
      const float* wr = W2 + (size_t)(nt * 16 + e) * 64 + ks * 32 + g * 8;
#pragma unroll
      for (int u = 0; u < 8; ++u) B2[ks][nt][u] = (__bf16)wr[u];
    }
  float b1c[4], g1c[4], be1c[4], b2c[4], g2c[4], be2c[4];
#pragma unroll
  for (int nt = 0; nt < 4; ++nt) {
    int c = nt * 16 + e;
    b1c[nt] = b1[c]; g1c[nt] = g1v[c]; be1c[nt] = be1[c];
    b2c[nt] = b2[c]; g2c[nt] = g2v[c]; be2c[nt] = be2[c];
  }

  // 8 nodes per wave; gather software pipeline: nbr index fetched 2 iterations
  // ahead (breaks the index->feature dependent chain), feature rows for node
  // it+1 issued before node it's compute. Named registers only.
  const int nodeBase = (blockIdx.x * 4 + wv) * 8;
  int jnext = (int)nbr[(size_t)(nodeBase + 1) * 16 + e];   // index for it+1
  const float* xi0p = x + (size_t)nodeBase * 64;
  const float* xj0p = x + (size_t)nbr[(size_t)nodeBase * 16 + e] * 64;
  float4 ci0a = *(const float4*)(xi0p + g * 8),      ci0b = *(const float4*)(xi0p + g * 8 + 4);
  float4 ci1a = *(const float4*)(xi0p + 32 + g * 8), ci1b = *(const float4*)(xi0p + 32 + g * 8 + 4);
  float4 cj0a = *(const float4*)(xj0p + g * 8),      cj0b = *(const float4*)(xj0p + g * 8 + 4);
  float4 cj1a = *(const float4*)(xj0p + 32 + g * 8), cj1b = *(const float4*)(xj0p + 32 + g * 8 + 4);

  for (int it = 0; it < 8; ++it) {
    const int node = nodeBase + it;
    // ---- prefetch phase (no consumer until next iteration) ----
    int jfar = 0;
    if (it < 6) jfar = (int)nbr[(size_t)(node + 2) * 16 + e];
    float4 ni0a, ni0b, ni1a, ni1b, nj0a, nj0b, nj1a, nj1b;
    if (it < 7) {
      const float* xin = x + (size_t)(node + 1) * 64;
      const float* xjn = x + (size_t)jnext * 64;   // jnext already resident
      ni0a = *(const float4*)(xin + g * 8);      ni0b = *(const float4*)(xin + g * 8 + 4);
      ni1a = *(const float4*)(xin + 32 + g * 8); ni1b = *(const float4*)(xin + 32 + g * 8 + 4);
      nj0a = *(const float4*)(xjn + g * 8);      nj0b = *(const float4*)(xjn + g * 8 + 4);
      nj1a = *(const float4*)(xjn + 32 + g * 8); nj1b = *(const float4*)(xjn + 32 + g * 8 + 4);
    }

    // ---- compute phase (current node, registers already resident) ----
    // feat = [x_i (k=0..63), x_j - x_i (k=64..127)]; A: lane holds A[row=e][k=ks*32+g*8+u]
    bf16x8 Af[4];
    Af[0] = pack8(ci0a, ci0b);
    Af[1] = pack8(ci1a, ci1b);
    Af[2] = pack8(sub4(cj0a, ci0a), sub4(cj0b, ci0b));
    Af[3] = pack8(sub4(cj1a, ci1a), sub4(cj1b, ci1b));

    f32x4 acc[4];
#pragma unroll
    for (int nt = 0; nt < 4; ++nt) acc[nt] = (f32x4){0.f, 0.f, 0.f, 0.f};
#pragma unroll
    for (int ks = 0; ks < 4; ++ks)
#pragma unroll
      for (int nt = 0; nt < 4; ++nt)
        acc[nt] = __builtin_amdgcn_mfma_f32_16x16x32_bf16(Af[ks], B1[ks][nt], acc[nt], 0, 0, 0);

    float nh[4][4];
    ln_relu(acc, b1c, g1c, be1c, nh);

    // transpose edge-major -> k-major via per-wave LDS tile.
    // Wave-synchronous: tr[wv] is private to this wave; in-order DS issue +
    // compiler-inserted lgkmcnt make barriers unnecessary.
    float* T = tr[wv];
#pragma unroll
    for (int nt = 0; nt < 4; ++nt)
#pragma unroll
      for (int j = 0; j < 4; ++j) T[(4 * g + j) * 68 + nt * 16 + e] = nh[nt][j];
    bf16x8 A2[2];
#pragma unroll
    for (int ks = 0; ks < 2; ++ks) {
      float4 ha = *(const float4*)(T + e * 68 + ks * 32 + g * 8);
      float4 hb = *(const float4*)(T + e * 68 + ks * 32 + g * 8 + 4);
      A2[ks] = pack8(ha, hb);
    }

    f32x4 acc2[4];
#pragma unroll
    for (int nt = 0; nt < 4; ++nt) acc2[nt] = (f32x4){0.f, 0.f, 0.f, 0.f};
#pragma unroll
    for (int ks = 0; ks < 2; ++ks)
#pragma unroll
      for (int nt = 0; nt < 4; ++nt)
        acc2[nt] = __builtin_amdgcn_mfma_f32_16x16x32_bf16(A2[ks], B2[ks][nt], acc2[nt], 0, 0, 0);

    float nh2[4][4];
    ln_relu(acc2, b2c, g2c, be2c, nh2);

    // mean over the 16 edge-rows
#pragma unroll
    for (int nt = 0; nt < 4; ++nt) {
      float p = nh2[nt][0] + nh2[nt][1] + nh2[nt][2] + nh2[nt][3];
      p += __shfl_xor(p, 16, 64);
      p += __shfl_xor(p, 32, 64);
      if (g == 0) out[(size_t)node * 64 + nt * 16 + e] = p * 0.0625f;
    }

    // ---- rotate pipeline registers ----
    if (it < 7) {
      ci0a = ni0a; ci0b = ni0b; ci1a = ni1a; ci1b = ni1b;
      cj0a = nj0a; cj0b = nj0b; cj1a = nj1a; cj1b = nj1b;
      jnext = jfar;
    }
  }
}

extern "C" void kernel_launch(void* const* d_in, const int* in_sizes, int n_in,
                              void* d_out, int out_size, void* d_ws, size_t ws_size,
                              hipStream_t stream) {
  (void)in_sizes; (void)n_in; (void)out_size; (void)ws_size;
  const float* x   = (const float*)d_in[0];
  // d_in[1..3] = edge_index, eta, phi: unused by the reference computation
  const float* Ws  = (const float*)d_in[4];
  const float* bs  = (const float*)d_in[5];
  const float* W1  = (const float*)d_in[6];
  const float* b1  = (const float*)d_in[7];
  const float* g1  = (const float*)d_in[8];
  const float* be1 = (const float*)d_in[9];
  const float* W2  = (const float*)d_in[10];
  const float* b2  = (const float*)d_in[11];
  const float* g2  = (const float*)d_in[12];
  const float* be2 = (const float*)d_in[13];
  float* out = (float*)d_out;

  char* ws = (char*)d_ws;
  __bf16* qvec = (__bf16*)(ws);                        // 16384*32*2 = 1MB
  __bf16* cvec = (__bf16*)(ws + 1048576);              // 1MB -> ends 2097152
  double* s64  = (double*)(ws + 2097152);              // 16384*8*8 = 1MB -> ends 3145728
  unsigned* partial   = (unsigned*)(ws + 3145728);     // 16384*256*4 = 16MB -> ends 19922944
  unsigned short* fin = (unsigned short*)(ws + 19922944);  // 16384*16*2 = 512KB

  k_proj<<<dim3(256), dim3(64), 0, stream>>>(x, Ws, bs, qvec, cvec, s64);
  k_dist<<<dim3(256, 4), dim3(256), 0, stream>>>(qvec, cvec, partial);
  k_merge<<<dim3(4096), dim3(256), 0, stream>>>(s64, partial, fin);
  k_mlp<<<dim3(512), dim3(256), 0, stream>>>(x, fin, W1, b1, g1, be1, W2, b2, g2, be2, out);
}

// Round 17
// 179.060 us; speedup vs baseline: 1.0128x; 1.0128x over previous
//
#include <hip/hip_runtime.h>

#define N_PTS 16384
#define KNN   16
#define CIN   64
#define SDIM  8

typedef __bf16 bf16x8 __attribute__((ext_vector_type(8)));
typedef float  f32x4  __attribute__((ext_vector_type(4)));

// ---------------- K1: s = x @ Ws^T + bs (f64 master for re-rank) + packed MFMA operand
// vectors for the distance GEMM.
// qvec[i] (K=32 bf16): [hi(8), hi(8), lo(8), sqi_hi, sqi_lo, 1, 1, 1, 0,0,0]
// cvec[j] (K=32 bf16): [-2hi(8), -2lo(8), -2hi(8), 1, 1, sqj_hi, sqj_lo, eps, 0,0,0]
// => dot = eps + sqi + sqj - 2*(a_hi b_hi + a_hi b_lo + a_lo b_hi) ~= d2 + eps > 0.
__global__ __launch_bounds__(64) void k_proj(
    const float* __restrict__ x, const float* __restrict__ Ws, const float* __restrict__ bs,
    __bf16* __restrict__ qvec, __bf16* __restrict__ cvec, double* __restrict__ s64) {
  __shared__ double w[SDIM * CIN];
  __shared__ double bsh[SDIM];
  int tid = threadIdx.x;
  for (int t = tid; t < SDIM * CIN; t += 64) w[t] = (double)Ws[t];
  if (tid < SDIM) bsh[tid] = (double)bs[tid];
  __syncthreads();
  int i = blockIdx.x * 64 + tid;
  double acc[SDIM];
#pragma unroll
  for (int d = 0; d < SDIM; ++d) acc[d] = bsh[d];
  for (int j = 0; j < CIN; j += 4) {
    float4 xv = *(const float4*)(x + (size_t)i * CIN + j);
#pragma unroll
    for (int d = 0; d < SDIM; ++d) {
      acc[d] = fma((double)xv.x, w[d * CIN + j + 0], acc[d]);
      acc[d] = fma((double)xv.y, w[d * CIN + j + 1], acc[d]);
      acc[d] = fma((double)xv.z, w[d * CIN + j + 2], acc[d]);
      acc[d] = fma((double)xv.w, w[d * CIN + j + 3], acc[d]);
    }
  }
  float sf[8];
  float sq = 0.f;
#pragma unroll
  for (int d = 0; d < SDIM; ++d) {
    sf[d] = (float)acc[d];
    s64[(size_t)i * SDIM + d] = acc[d];
    sq = fmaf(sf[d], sf[d], sq);
  }
  __bf16 av[32], bv[32];
#pragma unroll
  for (int d = 0; d < 8; ++d) {
    __bf16 hi = (__bf16)sf[d];
    float hif = (float)hi;
    __bf16 lo = (__bf16)(sf[d] - hif);
    av[d] = hi; av[8 + d] = hi; av[16 + d] = lo;
    __bf16 h2 = (__bf16)(-2.f * hif);          // exact (x2 is exponent bump)
    __bf16 l2 = (__bf16)(-2.f * (float)lo);    // exact
    bv[d] = h2; bv[8 + d] = l2; bv[16 + d] = h2;
  }
  __bf16 sqh = (__bf16)sq;
  __bf16 sql = (__bf16)(sq - (float)sqh);
  __bf16 one = (__bf16)1.0f, zero = (__bf16)0.0f;
  __bf16 eps = (__bf16)0.0009765625f;  // 2^-10, exact in bf16
  av[24] = sqh; av[25] = sql; av[26] = one; av[27] = one;
  av[28] = one; av[29] = av[30] = av[31] = zero;
  bv[24] = one; bv[25] = one; bv[26] = sqh; bv[27] = sql;
  bv[28] = eps; bv[29] = bv[30] = bv[31] = zero;
  uint4* ap = (uint4*)av;
  uint4* bpv = (uint4*)bv;
  uint4* da = (uint4*)(qvec + (size_t)i * 32);
  uint4* db = (uint4*)(cvec + (size_t)i * 32);
  da[0] = ap[0]; da[1] = ap[1]; da[2] = ap[2]; da[3] = ap[3];
  db[0] = bpv[0]; db[1] = bpv[1]; db[2] = bpv[2]; db[3] = bpv[3];
}

__device__ inline unsigned bitonic64(unsigned key, int lane) {
#pragma unroll
  for (int size = 2; size <= 64; size <<= 1) {
#pragma unroll
    for (int stride = size >> 1; stride > 0; stride >>= 1) {
      unsigned other = __shfl_xor(key, stride, 64);
      bool takeMin = (((lane & size) == 0) == ((lane & stride) == 0));
      unsigned mn = min(key, other), mx = max(key, other);
      key = takeMin ? mn : mx;
    }
  }
  return key;
}

// ---------------- K2: MFMA distance tiles, A=candidates(rows), B=queries(cols).
// 4 waves/block, double-buffered MFMA results, ring depth 32, branchless accept,
// clamp-free 4-op consume (d2+eps > 0 guaranteed by the eps K-slot).
// __launch_bounds__(256, 4): grid caps at 4 waves/SIMD; raising the VGPR target
// keeps the pipeline banks live. [R15 exact — best measured configuration]
__global__ __launch_bounds__(256, 4) void k_dist(
    const __bf16* __restrict__ qvec, const __bf16* __restrict__ cvec,
    unsigned* __restrict__ partial) {
  __shared__ unsigned ring[32 * 256];   // ring[slot*256+tid]: bank=tid%32, conflict-free
  const int tid = threadIdx.x;
  const int lane = tid & 63;
  const int wv = tid >> 6;
  const int e = lane & 15, g = lane >> 4;
  const int qidx = blockIdx.x * 64 + wv * 16 + e;   // this lane's query
  const int cbase = blockIdx.y * 4096;

  bf16x8 Qf = *(const bf16x8*)(qvec + (size_t)qidx * 32 + g * 8);  // B-frag (fixed)

  unsigned kk[16];
#pragma unroll
  for (int r = 0; r < 16; ++r) kk[r] = 0xFFFFFFFFu;
  float thr = __uint_as_float(0x7F800000u);  // +inf (shared across query quad)
  unsigned cnt = 0;

  const __bf16* cp = cvec + (size_t)(cbase + e) * 32 + g * 8;
  f32x4 zero4 = (f32x4){0.f, 0.f, 0.f, 0.f};
  const unsigned cb0 = (unsigned)(cbase + 4 * g);

  auto consume4 = [&](const f32x4& v, unsigned cb) {
#pragma unroll
    for (int j = 0; j < 4; ++j) {
      unsigned key = (__float_as_uint(v[j]) & 0xFFFFC000u) | (cb + j);  // v_and_or_b32
      ring[(cnt << 8) | (unsigned)tid] = key;     // unconditional write
      cnt += (v[j] < thr) ? 1u : 0u;              // branchless accept
    }
  };
  auto storm = [&]() {
#pragma unroll 1
    for (int i = 0; i < 32; ++i) {
      if (!__any(i < (int)cnt)) break;
      unsigned key = ring[(i << 8) | (unsigned)tid];
      if (i >= (int)cnt) key = 0xFFFFFFFFu;
      if (__any(key < kk[15])) {  // identity insert for key >= kk[15]
#pragma unroll
        for (int r = 15; r > 0; --r) kk[r] = max(kk[r - 1], min(kk[r], key));
        kk[0] = min(kk[0], key);
      }
    }
    cnt = 0;
    unsigned tbk = min((kk[15] >> 14) + 1u, 0x1FE00u);  // bucket+1, saturating
    thr = __uint_as_float(tbk << 14);
    // share: query-quad min of thresholds (lanes e, e+16, e+32, e+48)
    thr = fminf(thr, __shfl_xor(thr, 16, 64));
    thr = fminf(thr, __shfl_xor(thr, 32, 64));
  };

#define LOADG(B, grp) { const __bf16* np_ = cp + (size_t)(grp) * 2048;           \
    B##0 = *(const bf16x8*)(np_);        B##1 = *(const bf16x8*)(np_ + 512);     \
    B##2 = *(const bf16x8*)(np_ + 1024); B##3 = *(const bf16x8*)(np_ + 1536); }
#define MFMAG(C, B) {                                                            \
    C##0 = __builtin_amdgcn_mfma_f32_16x16x32_bf16(B##0, Qf, zero4, 0, 0, 0);    \
    C##1 = __builtin_amdgcn_mfma_f32_16x16x32_bf16(B##1, Qf, zero4, 0, 0, 0);    \
    C##2 = __builtin_amdgcn_mfma_f32_16x16x32_bf16(B##2, Qf, zero4, 0, 0, 0);    \
    C##3 = __builtin_amdgcn_mfma_f32_16x16x32_bf16(B##3, Qf, zero4, 0, 0, 0); }
#define CONSG(C, grp) { unsigned cb_ = cb0 + (unsigned)(grp) * 64u;              \
    consume4(C##0, cb_); consume4(C##1, cb_ + 16); consume4(C##2, cb_ + 32);     \
    consume4(C##3, cb_ + 48);                                                    \
    if (__any(cnt >= 17)) storm(); }

  bf16x8 a00, a01, a02, a03, a10, a11, a12, a13;
  f32x4 c00, c01, c02, c03, c10, c11, c12, c13;

  // 64 groups of 4 tiles (16 candidates/lane each), 2-group software pipeline
  LOADG(a0, 0)
  LOADG(a1, 1)
  MFMAG(c0, a0)                       // group 0 in flight
  for (int gr = 0; gr < 62; gr += 2) {
    LOADG(a0, gr + 2)                 // a0's MFMAs already issued
    MFMAG(c1, a1)                     // group gr+1 in flight
    CONSG(c0, gr)                     // consume landed group gr
    LOADG(a1, gr + 3)
    MFMAG(c0, a0)                     // group gr+2 in flight
    CONSG(c1, gr + 1)
  }
  MFMAG(c1, a1)                       // group 63
  CONSG(c0, 62)
  CONSG(c1, 63)
  storm();  // final flush -> kk sorted ascending
#undef LOADG
#undef MFMAG
#undef CONSG

  unsigned* p = partial + (size_t)qidx * 256 + (size_t)blockIdx.y * 64 + g * 16;
  *(uint4*)(p + 0)  = make_uint4(kk[0], kk[1], kk[2], kk[3]);
  *(uint4*)(p + 4)  = make_uint4(kk[4], kk[5], kk[6], kk[7]);
  *(uint4*)(p + 8)  = make_uint4(kk[8], kk[9], kk[10], kk[11]);
  *(uint4*)(p + 12) = make_uint4(kk[12], kk[13], kk[14], kk[15]);
}

// ---------------- K3: fused reduce (256 keys -> 64 via 4 bitonic-64) + exact f64 re-rank,
// bitonic sort on (d2,f64|idx), keep 16.
__global__ __launch_bounds__(256) void k_merge(
    const double* __restrict__ s64, const unsigned* __restrict__ partial,
    unsigned short* __restrict__ fin) {
  int lane = threadIdx.x & 63;
  int node = blockIdx.x * 4 + (threadIdx.x >> 6);
  unsigned jc = 0;
#pragma unroll
  for (int t = 0; t < 4; ++t) {
    unsigned key = partial[(size_t)node * 256 + t * 64 + lane];
    key = bitonic64(key, lane);
    unsigned k16 = __shfl(key, lane & 15, 64);  // top-16 live in lanes 0..15
    if ((lane >> 4) == t) jc = k16 & 0x3FFFu;
  }
  const double* si = s64 + (size_t)node * 8;
  const double* sj = s64 + (size_t)jc * 8;
  double d2 = 0.0;
#pragma unroll
  for (int d = 0; d < 8; ++d) { double t = si[d] - sj[d]; d2 = fma(t, t, d2); }
  unsigned long long key =
      (((unsigned long long)__double_as_longlong(d2)) & ~0x3FFFull) | (unsigned long long)jc;
#pragma unroll
  for (int size = 2; size <= 64; size <<= 1) {
#pragma unroll
    for (int stride = size >> 1; stride > 0; stride >>= 1) {
      unsigned lo = __shfl_xor((unsigned)key, stride, 64);
      unsigned hi = __shfl_xor((unsigned)(key >> 32), stride, 64);
      unsigned long long other = ((unsigned long long)hi << 32) | lo;
      bool takeMin = (((lane & size) == 0) == ((lane & stride) == 0));
      unsigned long long mn = key < other ? key : other;
      unsigned long long mx = key < other ? other : key;
      key = takeMin ? mn : mx;
    }
  }
  if (lane < 16) fin[(size_t)node * 16 + lane] = (unsigned short)(key & 0x3FFFull);
}

// ---------------- K4: gather + MLP (bf16 MFMA 16x16x32, f32 accum), LN, relu, mean over K
__device__ inline bf16x8 pack8(float4 a, float4 b) {
  bf16x8 r;
  r[0] = (__bf16)a.x; r[1] = (__bf16)a.y; r[2] = (__bf16)a.z; r[3] = (__bf16)a.w;
  r[4] = (__bf16)b.x; r[5] = (__bf16)b.y; r[6] = (__bf16)b.z; r[7] = (__bf16)b.w;
  return r;
}
__device__ inline float4 sub4(float4 a, float4 b) {
  return make_float4(a.x - b.x, a.y - b.y, a.z - b.z, a.w - b.w);
}
// LN over 64 channels of each edge-row, then affine + relu.
// acc[nt][j]: row (4*g + j), channel nt*16 + e  (C/D layout: col=lane&15, row=(lane>>4)*4+reg)
__device__ inline void ln_relu(const f32x4 acc[4], const float bc[4], const float gc[4],
                               const float bec[4], float nh[4][4]) {
#pragma unroll
  for (int j = 0; j < 4; ++j) {
    float v0 = acc[0][j] + bc[0], v1 = acc[1][j] + bc[1];
    float v2 = acc[2][j] + bc[2], v3 = acc[3][j] + bc[3];
    float t = v0 + v1 + v2 + v3;
    float qq = v0 * v0 + v1 * v1 + v2 * v2 + v3 * v3;
#pragma unroll
    for (int m = 1; m < 16; m <<= 1) {
      t += __shfl_xor(t, m, 64);
      qq += __shfl_xor(qq, m, 64);
    }
    float mean = t * (1.f / 64.f);
    float var = qq * (1.f / 64.f) - mean * mean;
    float rstd = rsqrtf(var + 1e-5f);
    nh[0][j] = fmaxf((v0 - mean) * rstd * gc[0] + bec[0], 0.f);
    nh[1][j] = fmaxf((v1 - mean) * rstd * gc[1] + bec[1], 0.f);
    nh[2][j] = fmaxf((v2 - mean) * rstd * gc[2] + bec[2], 0.f);
    nh[3][j] = fmaxf((v3 - mean) * rstd * gc[3] + bec[3], 0.f);
  }
}

// __launch_bounds__(256, 2): grid gives 2 waves/SIMD; raise VGPR cap so the
// gather software pipeline (2-deep nbr queue + next-node feature registers)
// survives register allocation.
__global__ __launch_bounds__(256, 2) void k_mlp(
    const float* __restrict__ x, const unsigned short* __restrict__ nbr,
    const float* __restrict__ W1, const float* __restrict__ b1,
    const float* __restrict__ g1v, const float* __restrict__ be1,
    const float* __restrict__ W2, const float* __restrict__ b2,
    const float* __restrict__ g2v, const float* __restrict__ be2,
    float* __restrict__ out) {
  __shared__ float tr[4][16 * 68];
  const int lane = threadIdx.x & 63;
  const int wv = threadIdx.x >> 6;
  const int e = lane & 15;  // A row (edge) / B,C col (channel within tile)
  const int g = lane >> 4;  // k-group of 8

  // B fragments: lane holds B[k=(lane>>4)*8+u][col=lane&15]; B[k][c] = W^T[k][c] = W[c][k]
  bf16x8 B1[4][4];
#pragma unroll
  for (int ks = 0; ks < 4; ++ks)
#pragma unroll
    for (int nt = 0; nt < 4; ++nt) {
      const float* wr = W1 + (size_t)(nt * 16 + e) * 128 + ks * 32 + g * 8;
#pragma unroll
      for (int u = 0; u < 8; ++u) B1[ks][nt][u] = (__bf16)wr[u];
    }
  bf16x8 B2[2][4];
#pragma unroll
  for (int ks = 0; ks < 2; ++ks)
#pragma unroll
    for (int nt = 0; nt < 4; ++nt) {
      const float* wr = W2 + (size_t)(nt * 16 + e) * 64 + ks * 32 + g * 8;
#pragma unroll
      for (int u = 0; u < 8; ++u) B2[ks][nt][u] = (__bf16)wr[u];
    }
  float b1c[4], g1c[4], be1c[4], b2c[4], g2c[4], be2c[4];
#pragma unroll
  for (int nt = 0; nt < 4; ++nt) {
    int c = nt * 16 + e;
    b1c[nt] = b1[c]; g1c[nt] = g1v[c]; be1c[nt] = be1[c];
    b2c[nt] = b2[c]; g2c[nt] = g2v[c]; be2c[nt] = be2[c];
  }

  // 8 nodes per wave; gather software pipeline: nbr index fetched 2 iterations
  // ahead (breaks the index->feature dependent chain), feature rows for node
  // it+1 issued before node it's compute. Named registers only.
  const int nodeBase = (blockIdx.x * 4 + wv) * 8;
  int jnext = (int)nbr[(size_t)(nodeBase + 1) * 16 + e];   // index for it+1
  const float* xi0p = x + (size_t)nodeBase * 64;
  const float* xj0p = x + (size_t)nbr[(size_t)nodeBase * 16 + e] * 64;
  float4 ci0a = *(const float4*)(xi0p + g * 8),      ci0b = *(const float4*)(xi0p + g * 8 + 4);
  float4 ci1a = *(const float4*)(xi0p + 32 + g * 8), ci1b = *(const float4*)(xi0p + 32 + g * 8 + 4);
  float4 cj0a = *(const float4*)(xj0p + g * 8),      cj0b = *(const float4*)(xj0p + g * 8 + 4);
  float4 cj1a = *(const float4*)(xj0p + 32 + g * 8), cj1b = *(const float4*)(xj0p + 32 + g * 8 + 4);

  for (int it = 0; it < 8; ++it) {
    const int node = nodeBase + it;
    // ---- prefetch phase (no consumer until next iteration) ----
    int jfar = 0;
    if (it < 6) jfar = (int)nbr[(size_t)(node + 2) * 16 + e];
    float4 ni0a, ni0b, ni1a, ni1b, nj0a, nj0b, nj1a, nj1b;
    if (it < 7) {
      const float* xin = x + (size_t)(node + 1) * 64;
      const float* xjn = x + (size_t)jnext * 64;   // jnext already resident
      ni0a = *(const float4*)(xin + g * 8);      ni0b = *(const float4*)(xin + g * 8 + 4);
      ni1a = *(const float4*)(xin + 32 + g * 8); ni1b = *(const float4*)(xin + 32 + g * 8 + 4);
      nj0a = *(const float4*)(xjn + g * 8);      nj0b = *(const float4*)(xjn + g * 8 + 4);
      nj1a = *(const float4*)(xjn + 32 + g * 8); nj1b = *(const float4*)(xjn + 32 + g * 8 + 4);
    }

    // ---- compute phase (current node, registers already resident) ----
    // feat = [x_i (k=0..63), x_j - x_i (k=64..127)]; A: lane holds A[row=e][k=ks*32+g*8+u]
    bf16x8 Af[4];
    Af[0] = pack8(ci0a, ci0b);
    Af[1] = pack8(ci1a, ci1b);
    Af[2] = pack8(sub4(cj0a, ci0a), sub4(cj0b, ci0b));
    Af[3] = pack8(sub4(cj1a, ci1a), sub4(cj1b, ci1b));

    f32x4 acc[4];
#pragma unroll
    for (int nt = 0; nt < 4; ++nt) acc[nt] = (f32x4){0.f, 0.f, 0.f, 0.f};
#pragma unroll
    for (int ks = 0; ks < 4; ++ks)
#pragma unroll
      for (int nt = 0; nt < 4; ++nt)
        acc[nt] = __builtin_amdgcn_mfma_f32_16x16x32_bf16(Af[ks], B1[ks][nt], acc[nt], 0, 0, 0);

    float nh[4][4];
    ln_relu(acc, b1c, g1c, be1c, nh);

    // transpose edge-major -> k-major via per-wave LDS tile.
    // Wave-synchronous: tr[wv] is private to this wave; in-order DS issue +
    // compiler-inserted lgkmcnt make barriers unnecessary.
    float* T = tr[wv];
#pragma unroll
    for (int nt = 0; nt < 4; ++nt)
#pragma unroll
      for (int j = 0; j < 4; ++j) T[(4 * g + j) * 68 + nt * 16 + e] = nh[nt][j];
    bf16x8 A2[2];
#pragma unroll
    for (int ks = 0; ks < 2; ++ks) {
      float4 ha = *(const float4*)(T + e * 68 + ks * 32 + g * 8);
      float4 hb = *(const float4*)(T + e * 68 + ks * 32 + g * 8 + 4);
      A2[ks] = pack8(ha, hb);
    }

    f32x4 acc2[4];
#pragma unroll
    for (int nt = 0; nt < 4; ++nt) acc2[nt] = (f32x4){0.f, 0.f, 0.f, 0.f};
#pragma unroll
    for (int ks = 0; ks < 2; ++ks)
#pragma unroll
      for (int nt = 0; nt < 4; ++nt)
        acc2[nt] = __builtin_amdgcn_mfma_f32_16x16x32_bf16(A2[ks], B2[ks][nt], acc2[nt], 0, 0, 0);

    float nh2[4][4];
    ln_relu(acc2, b2c, g2c, be2c, nh2);

    // mean over the 16 edge-rows
#pragma unroll
    for (int nt = 0; nt < 4; ++nt) {
      float p = nh2[nt][0] + nh2[nt][1] + nh2[nt][2] + nh2[nt][3];
      p += __shfl_xor(p, 16, 64);
      p += __shfl_xor(p, 32, 64);
      if (g == 0) out[(size_t)node * 64 + nt * 16 + e] = p * 0.0625f;
    }

    // ---- rotate pipeline registers ----
    if (it < 7) {
      ci0a = ni0a; ci0b = ni0b; ci1a = ni1a; ci1b = ni1b;
      cj0a = nj0a; cj0b = nj0b; cj1a = nj1a; cj1b = nj1b;
      jnext = jfar;
    }
  }
}

extern "C" void kernel_launch(void* const* d_in, const int* in_sizes, int n_in,
                              void* d_out, int out_size, void* d_ws, size_t ws_size,
                              hipStream_t stream) {
  (void)in_sizes; (void)n_in; (void)out_size; (void)ws_size;
  const float* x   = (const float*)d_in[0];
  // d_in[1..3] = edge_index, eta, phi: unused by the reference computation
  const float* Ws  = (const float*)d_in[4];
  const float* bs  = (const float*)d_in[5];
  const float* W1  = (const float*)d_in[6];
  const float* b1  = (const float*)d_in[7];
  const float* g1  = (const float*)d_in[8];
  const float* be1 = (const float*)d_in[9];
  const float* W2  = (const float*)d_in[10];
  const float* b2  = (const float*)d_in[11];
  const float* g2  = (const float*)d_in[12];
  const float* be2 = (const float*)d_in[13];
  float* out = (float*)d_out;

  char* ws = (char*)d_ws;
  __bf16* qvec = (__bf16*)(ws);                        // 16384*32*2 = 1MB
  __bf16* cvec = (__bf16*)(ws + 1048576);              // 1MB -> ends 2097152
  double* s64  = (double*)(ws + 2097152);              // 16384*8*8 = 1MB -> ends 3145728
  unsigned* partial   = (unsigned*)(ws + 3145728);     // 16384*256*4 = 16MB -> ends 19922944
  unsigned short* fin = (unsigned short*)(ws + 19922944);  // 16384*16*2 = 512KB

  k_proj<<<dim3(256), dim3(64), 0, stream>>>(x, Ws, bs, qvec, cvec, s64);
  k_dist<<<dim3(256, 4), dim3(256), 0, stream>>>(qvec, cvec, partial);
  k_merge<<<dim3(4096), dim3(256), 0, stream>>>(s64, partial, fin);
  k_mlp<<<dim3(512), dim3(256), 0, stream>>>(x, fin, W1, b1, g1, be1, W2, b2, g2, be2, out);
}